// Round 12
// baseline (196.923 us; speedup 1.0000x reference)
//
#include <hip/hip_runtime.h>
#include <cstdint>
#include <math.h>

typedef _Float16 f16;
typedef _Float16 f16x2 __attribute__((ext_vector_type(2)));
typedef _Float16 f16x4 __attribute__((ext_vector_type(4)));
typedef _Float16 f16x8 __attribute__((ext_vector_type(8)));
typedef __fp16   h16x2 __attribute__((ext_vector_type(2)));
typedef float    f32x4 __attribute__((ext_vector_type(4)));

__device__ __forceinline__ f32x4 mfma16(f16x8 a, f16x8 b, f32x4 c) {
  return __builtin_amdgcn_mfma_f32_16x16x32_f16(a, b, c, 0, 0, 0);
}
__device__ __forceinline__ void gl2lds16(const f16* g, f16* l) {
  __builtin_amdgcn_global_load_lds((__attribute__((address_space(1))) void*)(g),
                                   (__attribute__((address_space(3))) void*)(l),
                                   16, 0, 0);
}
__device__ __forceinline__ float fexp2(float x) { return __builtin_amdgcn_exp2f(x); }
__device__ __forceinline__ f16x2 pkrtz(float a, float b) {
  h16x2 r = __builtin_amdgcn_cvt_pkrtz(a, b);
  return __builtin_bit_cast(f16x2, r);
}
__device__ __forceinline__ float dot2acc(f16x2 a, f16x2 b, float c) {
#if __has_builtin(__builtin_amdgcn_fdot2)
  return __builtin_amdgcn_fdot2(__builtin_bit_cast(h16x2, a),
                                __builtin_bit_cast(h16x2, b), c, false);
#else
  return c + (float)a[0] * (float)b[0] + (float)a[1] * (float)b[1];
#endif
}

// ---------------- fp32 -> f16 conversion ----------------
// Dense 1D grid: 4096 fully-active blocks.
__global__ __launch_bounds__(256) void cvt_kernel(
    const float* __restrict__ x,  const float* __restrict__ wq, const float* __restrict__ wk,
    const float* __restrict__ wv, const float* __restrict__ wo,
    f16* __restrict__ xh, f16* __restrict__ wqkvh, f16* __restrict__ woh)
{
  const int blk = blockIdx.x;
  const float* src; f16* dst; int off;
  if (blk < 2048)      { src = x;  dst = xh;              off = blk; }
  else {
    const int wseg = (blk - 2048) >> 9;       // 0..3
    off = (blk - 2048) & 511;
    if      (wseg == 0) { src = wq; dst = wqkvh; }
    else if (wseg == 1) { src = wk; dst = wqkvh + 1048576; }
    else if (wseg == 2) { src = wv; dst = wqkvh + 2097152; }
    else                { src = wo; dst = woh; }
  }
  const int idx = off * 2048 + (int)threadIdx.x * 8;
  f32x4 a = *(const f32x4*)(src + idx);
  f32x4 b = *(const f32x4*)(src + idx + 4);
  f16x8 h;
  h[0] = (f16)a[0]; h[1] = (f16)a[1]; h[2] = (f16)a[2]; h[3] = (f16)a[3];
  h[4] = (f16)b[0]; h[5] = (f16)b[1]; h[6] = (f16)b[2]; h[7] = (f16)b[3];
  *(f16x8*)(dst + idx) = h;
}

// ---------------- QKV GEMM: 128x128, BK=32, TRIPLE-buffer counted-vmcnt ----
// R12: 1-deep prefetch + __syncthreads (implicit vmcnt(0)) exposed staging
// latency every K-step (T3/T4 diagnosis). Now: 3 LDS buffers, stage(k+2)
// issued AFTER the barrier (so it can't race compute(k-1) on that buffer),
// waits are counted: vmcnt(4) retires only the 4 oldest loads (= this step's
// buffer); next-step loads stay in flight across the raw s_barrier. Last
// step uses vmcnt(0). vmcnt waits oldest-first (m135); cross-wave visibility:
// wave A confirms its own loads at iter k+2's vmcnt BEFORE the barrier wave B
// reads behind. LDS 48KB -> 3 blocks/CU (grid 768 = exactly 3/CU).
__global__ __launch_bounds__(256) void gemm_qkv(
    const f16* __restrict__ A, const f16* __restrict__ B,
    const float* __restrict__ bias0, const float* __restrict__ bias1, const float* __restrict__ bias2,
    f16* __restrict__ Qp, f16* __restrict__ Kp, f16* __restrict__ Vtp)
{
  constexpr int K = 1024;
  __shared__ __align__(16) f16 As[3][128 * 32];
  __shared__ __align__(16) f16 Bs[3][128 * 32];
  const int tid  = threadIdx.x;
  const int wave = tid >> 6, lane = tid & 63;
  const int quad = lane >> 4, col = lane & 15;
  const int tile_m = blockIdx.y * 128, tile_n = blockIdx.x * 128;
  const int mb = (wave >> 1) * 64, nb = (wave & 1) * 64;
  const int srow = lane >> 2, scol = (lane & 3) * 8;
  const f16* gA = A + (size_t)(tile_m + wave * 32 + srow) * K + scol;
  const f16* gB = B + (size_t)(tile_n + wave * 32 + srow) * K + scol;

  auto stage = [&](int buf, int k0) {        // 4 glds per wave
    gl2lds16(gA + k0,          &As[buf][wave * 1024]);
    gl2lds16(gA + 16 * K + k0, &As[buf][wave * 1024 + 512]);
    gl2lds16(gB + k0,          &Bs[buf][wave * 1024]);
    gl2lds16(gB + 16 * K + k0, &Bs[buf][wave * 1024 + 512]);
  };

  f32x4 acc[4][4] = {};
  stage(0, 0);
  stage(1, 32);
  for (int k0 = 0; k0 < K; k0 += 32) {
    const int cb = (k0 >> 5) % 3;
    // retire only THIS step's 4 loads (oldest); keep next step's in flight
    if (k0 + 32 < K) { __asm__ volatile("s_waitcnt vmcnt(4)" ::: "memory"); }
    else             { __asm__ volatile("s_waitcnt vmcnt(0)" ::: "memory"); }
    __builtin_amdgcn_s_barrier();            // buf[cb] ready for all waves
    if (k0 + 64 < K) stage((cb + 2) % 3, k0 + 64);  // 2-deep prefetch
    f16x8 af[4], bf[4];
    #pragma unroll
    for (int i = 0; i < 4; ++i)
      af[i] = *(const f16x8*)&As[cb][(mb + i * 16 + col) * 32 + quad * 8];
    #pragma unroll
    for (int j = 0; j < 4; ++j)
      bf[j] = *(const f16x8*)&Bs[cb][(nb + j * 16 + col) * 32 + quad * 8];
    #pragma unroll
    for (int i = 0; i < 4; ++i)
      #pragma unroll
      for (int j = 0; j < 4; ++j)
        acc[i][j] = mfma16(af[i], bf[j], acc[i][j]);
  }

  #pragma unroll
  for (int j = 0; j < 4; ++j) {
    const int gn = tile_n + nb + j * 16 + col;
    const int which = gn >> 10;
    const int d = gn & 1023;
    const int h = d >> 6, hi = d & 63;
    if (which == 2) {
      // V -> transposed [bb][h][hi][s], packed f16x4 along s
      const float bvv = bias2[d];
      #pragma unroll
      for (int i = 0; i < 4; ++i) {
        const int gm = tile_m + mb + i * 16 + quad * 4;   // r=0; s run of 4
        const int bb = gm >> 11, s = gm & 2047;
        f16x4 pw;
        #pragma unroll
        for (int r = 0; r < 4; ++r) pw[r] = (f16)(acc[i][j][r] + bvv);
        *(f16x4*)&Vtp[(((size_t)bb * 16 + h) * 64 + hi) * 2048 + s] = pw;
      }
    } else {
      const float* bp = (which == 0) ? bias0 : bias1;
      f16* dst        = (which == 0) ? Qp    : Kp;
      const float bvv = bp[d];
      const float qs  = (which == 0) ? 0.18033688f : 1.0f;  // 1/sqrt(64)*log2(e) in Q
      #pragma unroll
      for (int i = 0; i < 4; ++i) {
        #pragma unroll
        for (int r = 0; r < 4; ++r) {
          const int gm = tile_m + mb + i * 16 + quad * 4 + r;
          const int bb = gm >> 11, s = gm & 2047;
          dst[(((size_t)bb * 16 + h) * 2048 + s) * 64 + hi] = (f16)((acc[i][j][r] + bvv) * qs);
        }
      }
    }
  }
}

// ---------------- flash attention, merged tile-pair, static-max softmax ----
// Byte-identical to R8-R11 (verified ~45us).
__global__ __launch_bounds__(256, 4) void attn_kernel(
    const f16* __restrict__ Q, const f16* __restrict__ K, const f16* __restrict__ Vt,
    f16* __restrict__ ctx)
{
  __shared__ __align__(16) f16 Ks[2][64 * 72];     // [buf][kv][d], pad 72
  __shared__ __align__(16) f16 Vts[2][64 * 72];    // [buf][d][kv], pad 72
  __shared__ __align__(16) f16 Ps[4][2][16 * 72];  // per-wave, per-tile P

  const int bh  = blockIdx.x;                      // x = bh -> XCD = bh%8 (R6)
  const int yy  = blockIdx.y;
  const int p   = (yy < 8) ? yy : 23 - yy;         // CU pair (yy,yy+8): p+p'=15
  const int qlong = 31 - p, qshort = p;
  const int tid = threadIdx.x;
  const int wave = tid >> 6, lane = tid & 63;
  const int quad = lane >> 4, col = lane & 15;
  const int b = bh >> 4, h = bh & 15;
  const size_t base = (size_t)bh * 2048 * 64;
  const size_t vtb  = (size_t)bh * 64 * 2048;

  // staging map: 512 16B-chunks per tensor, 2 per thread
  int srow[2], sc8[2];
  #pragma unroll
  for (int i = 0; i < 2; ++i) {
    const int flat = tid + i * 256;
    srow[i] = flat >> 3;
    sc8[i]  = (flat & 7) * 8;
  }

  const int qa = qlong * 64 + wave * 16;    // long tile rows (always active)
  const int qb = qshort * 64 + wave * 16;   // short tile rows (active t<=qshort)
  const f16x8 bqa0 = *(const f16x8*)&Q[base + (size_t)(qa + col) * 64 + quad * 8];
  const f16x8 bqa1 = *(const f16x8*)&Q[base + (size_t)(qa + col) * 64 + 32 + quad * 8];
  const f16x8 bqb0 = *(const f16x8*)&Q[base + (size_t)(qb + col) * 64 + quad * 8];
  const f16x8 bqb1 = *(const f16x8*)&Q[base + (size_t)(qb + col) * 64 + 32 + quad * 8];

  f32x4 cta[4] = {}, ctb[4] = {};
  float la = 0.f, lb2 = 0.f;                // quad-partial row sums

  f16x8 kr[2], vr[2];
  auto gload = [&](int t) {
    #pragma unroll
    for (int i = 0; i < 2; ++i) {
      kr[i] = *(const f16x8*)&K[base + (size_t)(t * 64 + srow[i]) * 64 + sc8[i]];
      vr[i] = *(const f16x8*)&Vt[vtb + (size_t)srow[i] * 2048 + t * 64 + sc8[i]];
    }
  };
  auto swrite = [&](int buf) {
    #pragma unroll
    for (int i = 0; i < 2; ++i) {
      *(f16x8*)&Ks[buf][srow[i] * 72 + sc8[i]]  = kr[i];
      *(f16x8*)&Vts[buf][srow[i] * 72 + sc8[i]] = vr[i];
    }
  };

  const int nIter = qlong + 1;               // 17..32

  // prologue: stage tile 0 into buf0, prefetch tile 1 into regs
  gload(0);
  __syncthreads();
  swrite(0);
  gload(1);                                  // nIter >= 17 always

  for (int t = 0; t < nIter; ++t) {
    const int cur = t & 1;
    __syncthreads();                         // buf[cur] staged; own vmcnt drained
    if (t + 1 < nIter) {
      swrite(cur ^ 1);                       // stage next tile
      if (t + 2 < nIter) gload(t + 2);       // refill regs
    }
    const bool doB = (t <= qshort);

    // S^T = K Q^T for both tiles; ak frags shared from registers
    f32x4 sa[4], sb[4];
    #pragma unroll
    for (int jt = 0; jt < 4; ++jt) {
      const int kro = (jt * 16 + col) * 72;
      const f16x8 ak0 = *(const f16x8*)&Ks[cur][kro + quad * 8];
      const f16x8 ak1 = *(const f16x8*)&Ks[cur][kro + 32 + quad * 8];
      f32x4 za = {};
      za = mfma16(ak0, bqa0, za);
      sa[jt] = mfma16(ak1, bqa1, za);
      if (doB) {
        f32x4 zb = {};
        zb = mfma16(ak0, bqb0, zb);
        sb[jt] = mfma16(ak1, bqb1, zb);
      }
    }

    if (t == qlong) {   // long tile diagonal (last iteration)
      #pragma unroll
      for (int jt = 0; jt < 4; ++jt) {
        const int kg = t * 64 + jt * 16 + quad * 4;
        #pragma unroll
        for (int r = 0; r < 4; ++r)
          if (kg + r > qa + col) sa[jt][r] = -1e30f;
      }
    }
    if (t == qshort) {  // short tile diagonal
      #pragma unroll
      for (int jt = 0; jt < 4; ++jt) {
        const int kg = t * 64 + jt * 16 + quad * 4;
        #pragma unroll
        for (int r = 0; r < 4; ++r)
          if (kg + r > qb + col) sb[jt][r] = -1e30f;
      }
    }

    const f16x2 one2 = {(_Float16)1.f, (_Float16)1.f};

    // ---- P = exp2(s) (static-max), long tile -> Ps slot 0 ----
    {
      float rs = 0.f;
      #pragma unroll
      for (int jt = 0; jt < 4; ++jt) {
        const f16x2 a01 = pkrtz(fexp2(sa[jt][0]), fexp2(sa[jt][1]));
        const f16x2 a23 = pkrtz(fexp2(sa[jt][2]), fexp2(sa[jt][3]));
        rs = dot2acc(a01, one2, rs);
        rs = dot2acc(a23, one2, rs);
        f16x4 pw; pw[0] = a01[0]; pw[1] = a01[1]; pw[2] = a23[0]; pw[3] = a23[1];
        *(f16x4*)&Ps[wave][0][col * 72 + jt * 16 + quad * 4] = pw;
      }
      la += rs;
    }

    // ---- P = exp2(s), short tile -> Ps slot 1 ----
    if (doB) {
      float rs = 0.f;
      #pragma unroll
      for (int jt = 0; jt < 4; ++jt) {
        const f16x2 a01 = pkrtz(fexp2(sb[jt][0]), fexp2(sb[jt][1]));
        const f16x2 a23 = pkrtz(fexp2(sb[jt][2]), fexp2(sb[jt][3]));
        rs = dot2acc(a01, one2, rs);
        rs = dot2acc(a23, one2, rs);
        f16x4 pw; pw[0] = a01[0]; pw[1] = a01[1]; pw[2] = a23[0]; pw[3] = a23[1];
        *(f16x4*)&Ps[wave][1][col * 72 + jt * 16 + quad * 4] = pw;
      }
      lb2 += rs;
    }

    __asm__ volatile("s_waitcnt lgkmcnt(0)" ::: "memory");  // in-wave P RAW drain

    // ---- ctx += P V (bv frags shared from registers) ----
    const f16x8 apa0 = *(const f16x8*)&Ps[wave][0][col * 72 + quad * 8];
    const f16x8 apa1 = *(const f16x8*)&Ps[wave][0][col * 72 + 32 + quad * 8];
    if (doB) {
      const f16x8 apb0 = *(const f16x8*)&Ps[wave][1][col * 72 + quad * 8];
      const f16x8 apb1 = *(const f16x8*)&Ps[wave][1][col * 72 + 32 + quad * 8];
      #pragma unroll
      for (int jd = 0; jd < 4; ++jd) {
        const int vro = (jd * 16 + col) * 72;
        const f16x8 bv0 = *(const f16x8*)&Vts[cur][vro + quad * 8];
        const f16x8 bv1 = *(const f16x8*)&Vts[cur][vro + 32 + quad * 8];
        cta[jd] = mfma16(apa1, bv1, mfma16(apa0, bv0, cta[jd]));
        ctb[jd] = mfma16(apb1, bv1, mfma16(apb0, bv0, ctb[jd]));
      }
    } else {
      #pragma unroll
      for (int jd = 0; jd < 4; ++jd) {
        const int vro = (jd * 16 + col) * 72;
        const f16x8 bv0 = *(const f16x8*)&Vts[cur][vro + quad * 8];
        const f16x8 bv1 = *(const f16x8*)&Vts[cur][vro + 32 + quad * 8];
        cta[jd] = mfma16(apa1, bv1, mfma16(apa0, bv0, cta[jd]));
      }
    }
  }

  // ---- epilogue, long tile ----
  {
    la += __shfl_xor(la, 16);
    la += __shfl_xor(la, 32);
    f32x4 lva;
    #pragma unroll
    for (int r = 0; r < 4; ++r) lva[r] = __shfl(la, quad * 4 + r);
    #pragma unroll
    for (int jd = 0; jd < 4; ++jd) {
      #pragma unroll
      for (int r = 0; r < 4; ++r) {
        const int qga = qa + quad * 4 + r;
        const int d = h * 64 + jd * 16 + col;
        ctx[((size_t)b * 2048 + qga) * 1024 + d] = (f16)(cta[jd][r] / lva[r]);
      }
    }
  }
  // ---- epilogue, short tile ----
  {
    lb2 += __shfl_xor(lb2, 16);
    lb2 += __shfl_xor(lb2, 32);
    f32x4 lvb;
    #pragma unroll
    for (int r = 0; r < 4; ++r) lvb[r] = __shfl(lb2, quad * 4 + r);
    #pragma unroll
    for (int jd = 0; jd < 4; ++jd) {
      #pragma unroll
      for (int r = 0; r < 4; ++r) {
        const int qgb = qb + quad * 4 + r;
        const int d = h * 64 + jd * 16 + col;
        ctx[((size_t)b * 2048 + qgb) * 1024 + d] = (f16)(ctb[jd][r] / lvb[r]);
      }
    }
  }
}

// ---------------- O projection: 128x64, BK=64, TRIPLE-buffer counted-vmcnt -
// Same counted-vmcnt scheme as gemm_qkv; 6 glds per stage -> vmcnt(6).
// LDS 72KB -> 2 blocks/CU (grid 512 = exactly 2/CU).
__global__ __launch_bounds__(256) void gemm_o(
    const f16* __restrict__ A, const f16* __restrict__ B, const float* __restrict__ bias,
    float* __restrict__ Out)
{
  constexpr int K = 1024;
  __shared__ __align__(16) f16 As[3][2][128 * 32];   // [buf][ks][row][32]
  __shared__ __align__(16) f16 Bs[3][2][64 * 32];    // [buf][ks][row][32]
  const int tid  = threadIdx.x;
  const int wave = tid >> 6, lane = tid & 63;
  const int quad = lane >> 4, col = lane & 15;
  const int tile_m = blockIdx.y * 128, tile_n = blockIdx.x * 64;
  const int mb = wave * 32;
  const int srow = lane >> 2, scol = (lane & 3) * 8;   // 16 rows x 32 cols per call
  const f16* gA = A + (size_t)(tile_m + srow) * K + scol;
  const f16* gB = B + (size_t)(tile_n + srow) * K + scol;

  auto stage = [&](int buf, int k0) {        // 6 glds per wave
    #pragma unroll
    for (int ks = 0; ks < 2; ++ks) {
      #pragma unroll
      for (int i = 0; i < 2; ++i)
        gl2lds16(gA + (size_t)(wave * 32 + i * 16) * K + k0 + ks * 32,
                 &As[buf][ks][(wave * 32 + i * 16) * 32]);
      gl2lds16(gB + (size_t)(wave * 16) * K + k0 + ks * 32,
               &Bs[buf][ks][(wave * 16) * 32]);
    }
  };

  f32x4 acc[2][4] = {};
  stage(0, 0);
  stage(1, 64);
  for (int k0 = 0; k0 < K; k0 += 64) {
    const int cb = (k0 >> 6) % 3;
    if (k0 + 64 < K) { __asm__ volatile("s_waitcnt vmcnt(6)" ::: "memory"); }
    else             { __asm__ volatile("s_waitcnt vmcnt(0)" ::: "memory"); }
    __builtin_amdgcn_s_barrier();            // buf[cb] ready for all waves
    if (k0 + 128 < K) stage((cb + 2) % 3, k0 + 128);  // 2-deep prefetch
    #pragma unroll
    for (int ks = 0; ks < 2; ++ks) {
      f16x8 af[2], bf[4];
      #pragma unroll
      for (int i = 0; i < 2; ++i)
        af[i] = *(const f16x8*)&As[cb][ks][(mb + i * 16 + col) * 32 + quad * 8];
      #pragma unroll
      for (int j = 0; j < 4; ++j)
        bf[j] = *(const f16x8*)&Bs[cb][ks][(j * 16 + col) * 32 + quad * 8];
      #pragma unroll
      for (int i = 0; i < 2; ++i)
        #pragma unroll
        for (int j = 0; j < 4; ++j)
          acc[i][j] = mfma16(af[i], bf[j], acc[i][j]);
    }
  }

  #pragma unroll
  for (int j = 0; j < 4; ++j) {
    const int gn = tile_n + j * 16 + col;
    const float bvv = bias[gn];
    #pragma unroll
    for (int i = 0; i < 2; ++i) {
      #pragma unroll
      for (int r = 0; r < 4; ++r) {
        const int gm = tile_m + mb + i * 16 + quad * 4 + r;
        Out[(size_t)gm * 1024 + gn] = acc[i][j][r] + bvv;
      }
    }
  }
}

extern "C" void kernel_launch(void* const* d_in, const int* in_sizes, int n_in,
                              void* d_out, int out_size, void* d_ws, size_t ws_size,
                              hipStream_t stream)
{
  const float* x  = (const float*)d_in[0];
  const float* Wq = (const float*)d_in[1];
  const float* bq = (const float*)d_in[2];
  const float* Wk = (const float*)d_in[3];
  const float* bk = (const float*)d_in[4];
  const float* Wv = (const float*)d_in[5];
  const float* bv = (const float*)d_in[6];
  const float* Wo = (const float*)d_in[7];
  const float* bo = (const float*)d_in[8];
  float* out = (float*)d_out;

  f16* ws = (f16*)d_ws;
  const size_t M1 = 1048576;
  f16* xh    = ws;             // 4M halves
  f16* wqkvh = ws + 4  * M1;   // 3M
  f16* woh   = ws + 7  * M1;   // 1M
  f16* Qh    = ws + 8  * M1;   // 4M  [B,H,S,64] (pre-scaled)
  f16* Kh    = ws + 12 * M1;   // 4M  [B,H,S,64]
  f16* Vth   = ws + 20 * M1;   // 4M  [B,H,64,S] (written directly by gemm_qkv)
  f16* ctxh  = ws + 24 * M1;   // 4M  [B,S,D]

  cvt_kernel<<<4096, 256, 0, stream>>>(x, Wq, Wk, Wv, Wo, xh, wqkvh, woh);
  gemm_qkv<<<dim3(24, 32), 256, 0, stream>>>(xh, wqkvh, bq, bk, bv, Qh, Kh, Vth);
  attn_kernel<<<dim3(32, 16), 256, 0, stream>>>(Qh, Kh, Vth, ctxh);
  gemm_o<<<dim3(16, 32), 256, 0, stream>>>(ctxh, woh, bo, out);
}

// Round 13
// 184.867 us; speedup vs baseline: 1.0652x; 1.0652x over previous
//
#include <hip/hip_runtime.h>
#include <cstdint>
#include <math.h>

typedef _Float16 f16;
typedef _Float16 f16x2 __attribute__((ext_vector_type(2)));
typedef _Float16 f16x4 __attribute__((ext_vector_type(4)));
typedef _Float16 f16x8 __attribute__((ext_vector_type(8)));
typedef __fp16   h16x2 __attribute__((ext_vector_type(2)));
typedef float    f32x4 __attribute__((ext_vector_type(4)));

__device__ __forceinline__ f32x4 mfma16(f16x8 a, f16x8 b, f32x4 c) {
  return __builtin_amdgcn_mfma_f32_16x16x32_f16(a, b, c, 0, 0, 0);
}
__device__ __forceinline__ void gl2lds16(const f16* g, f16* l) {
  __builtin_amdgcn_global_load_lds((__attribute__((address_space(1))) void*)(g),
                                   (__attribute__((address_space(3))) void*)(l),
                                   16, 0, 0);
}
__device__ __forceinline__ float fexp2(float x) { return __builtin_amdgcn_exp2f(x); }
__device__ __forceinline__ f16x2 pkrtz(float a, float b) {
  h16x2 r = __builtin_amdgcn_cvt_pkrtz(a, b);
  return __builtin_bit_cast(f16x2, r);
}
__device__ __forceinline__ float dot2acc(f16x2 a, f16x2 b, float c) {
#if __has_builtin(__builtin_amdgcn_fdot2)
  return __builtin_amdgcn_fdot2(__builtin_bit_cast(h16x2, a),
                                __builtin_bit_cast(h16x2, b), c, false);
#else
  return c + (float)a[0] * (float)b[0] + (float)a[1] * (float)b[1];
#endif
}

// ---------------- fp32 -> f16 conversion ----------------
// Dense 1D grid: 4096 fully-active blocks.
__global__ __launch_bounds__(256) void cvt_kernel(
    const float* __restrict__ x,  const float* __restrict__ wq, const float* __restrict__ wk,
    const float* __restrict__ wv, const float* __restrict__ wo,
    f16* __restrict__ xh, f16* __restrict__ wqkvh, f16* __restrict__ woh)
{
  const int blk = blockIdx.x;
  const float* src; f16* dst; int off;
  if (blk < 2048)      { src = x;  dst = xh;              off = blk; }
  else {
    const int wseg = (blk - 2048) >> 9;       // 0..3
    off = (blk - 2048) & 511;
    if      (wseg == 0) { src = wq; dst = wqkvh; }
    else if (wseg == 1) { src = wk; dst = wqkvh + 1048576; }
    else if (wseg == 2) { src = wv; dst = wqkvh + 2097152; }
    else                { src = wo; dst = woh; }
  }
  const int idx = off * 2048 + (int)threadIdx.x * 8;
  f32x4 a = *(const f32x4*)(src + idx);
  f32x4 b = *(const f32x4*)(src + idx + 4);
  f16x8 h;
  h[0] = (f16)a[0]; h[1] = (f16)a[1]; h[2] = (f16)a[2]; h[3] = (f16)a[3];
  h[4] = (f16)b[0]; h[5] = (f16)b[1]; h[6] = (f16)b[2]; h[7] = (f16)b[3];
  *(f16x8*)(dst + idx) = h;
}

// ---------------- QKV GEMM: 128x128 tile, BK=32, dbuf 1-barrier ----------
// REVERTED to R11 (known-good): __syncthreads dbuf, stage-after-barrier.
// R12's counted-vmcnt triple-buffer REGRESSED this kernel 42->56us: the
// opaque per-iter asm fence blocked the compiler's ds_read/MFMA interleave
// (m141 failure mode; T4 only pays inside a full 8-phase structure).
// V written directly in transposed layout [bh][d][s] (vtrans deleted, R10).
__global__ __launch_bounds__(256) void gemm_qkv(
    const f16* __restrict__ A, const f16* __restrict__ B,
    const float* __restrict__ bias0, const float* __restrict__ bias1, const float* __restrict__ bias2,
    f16* __restrict__ Qp, f16* __restrict__ Kp, f16* __restrict__ Vtp)
{
  constexpr int K = 1024;
  __shared__ __align__(16) f16 As[2][128 * 32];
  __shared__ __align__(16) f16 Bs[2][128 * 32];
  const int tid  = threadIdx.x;
  const int wave = tid >> 6, lane = tid & 63;
  const int quad = lane >> 4, col = lane & 15;
  const int tile_m = blockIdx.y * 128, tile_n = blockIdx.x * 128;
  const int mb = (wave >> 1) * 64, nb = (wave & 1) * 64;
  const int srow = lane >> 2, scol = (lane & 3) * 8;
  const f16* gA = A + (size_t)(tile_m + wave * 32 + srow) * K + scol;
  const f16* gB = B + (size_t)(tile_n + wave * 32 + srow) * K + scol;

  auto stage = [&](int buf, int k0) {
    gl2lds16(gA + k0,          &As[buf][wave * 1024]);
    gl2lds16(gA + 16 * K + k0, &As[buf][wave * 1024 + 512]);
    gl2lds16(gB + k0,          &Bs[buf][wave * 1024]);
    gl2lds16(gB + 16 * K + k0, &Bs[buf][wave * 1024 + 512]);
  };

  f32x4 acc[4][4] = {};
  stage(0, 0);
  for (int k0 = 0; k0 < K; k0 += 32) {
    const int cur = (k0 >> 5) & 1;
    __syncthreads();                     // buf[cur] landed (barrier drains vmcnt)
    if (k0 + 32 < K) stage(cur ^ 1, k0 + 32);   // overlap with compute below
    f16x8 af[4], bf[4];
    #pragma unroll
    for (int i = 0; i < 4; ++i)
      af[i] = *(const f16x8*)&As[cur][(mb + i * 16 + col) * 32 + quad * 8];
    #pragma unroll
    for (int j = 0; j < 4; ++j)
      bf[j] = *(const f16x8*)&Bs[cur][(nb + j * 16 + col) * 32 + quad * 8];
    #pragma unroll
    for (int i = 0; i < 4; ++i)
      #pragma unroll
      for (int j = 0; j < 4; ++j)
        acc[i][j] = mfma16(af[i], bf[j], acc[i][j]);
  }

  #pragma unroll
  for (int j = 0; j < 4; ++j) {
    const int gn = tile_n + nb + j * 16 + col;
    const int which = gn >> 10;
    const int d = gn & 1023;
    const int h = d >> 6, hi = d & 63;
    if (which == 2) {
      // V -> transposed [bb][h][hi][s], packed f16x4 along s
      const float bvv = bias2[d];
      #pragma unroll
      for (int i = 0; i < 4; ++i) {
        const int gm = tile_m + mb + i * 16 + quad * 4;   // r=0; s run of 4
        const int bb = gm >> 11, s = gm & 2047;
        f16x4 pw;
        #pragma unroll
        for (int r = 0; r < 4; ++r) pw[r] = (f16)(acc[i][j][r] + bvv);
        *(f16x4*)&Vtp[(((size_t)bb * 16 + h) * 64 + hi) * 2048 + s] = pw;
      }
    } else {
      const float* bp = (which == 0) ? bias0 : bias1;
      f16* dst        = (which == 0) ? Qp    : Kp;
      const float bvv = bp[d];
      const float qs  = (which == 0) ? 0.18033688f : 1.0f;  // 1/sqrt(64)*log2(e) in Q
      #pragma unroll
      for (int i = 0; i < 4; ++i) {
        #pragma unroll
        for (int r = 0; r < 4; ++r) {
          const int gm = tile_m + mb + i * 16 + quad * 4 + r;
          const int bb = gm >> 11, s = gm & 2047;
          dst[(((size_t)bb * 16 + h) * 2048 + s) * 64 + hi] = (f16)((acc[i][j][r] + bvv) * qs);
        }
      }
    }
  }
}

// ---------------- flash attention, merged tile-pair, static-max softmax ----
// R8 body + T5 s_setprio(1) around the MFMA clusters (QK, PV). Mechanism:
// 2 independent blocks/CU drift freely -> scheduler can favor the MFMA-phase
// wave over the other block's memory/VALU waves (m191: +4-7% attn; m190:
// null on barrier-locked GEMM, so GEMMs get none).
__global__ __launch_bounds__(256, 4) void attn_kernel(
    const f16* __restrict__ Q, const f16* __restrict__ K, const f16* __restrict__ Vt,
    f16* __restrict__ ctx)
{
  __shared__ __align__(16) f16 Ks[2][64 * 72];     // [buf][kv][d], pad 72
  __shared__ __align__(16) f16 Vts[2][64 * 72];    // [buf][d][kv], pad 72
  __shared__ __align__(16) f16 Ps[4][2][16 * 72];  // per-wave, per-tile P

  const int bh  = blockIdx.x;                      // x = bh -> XCD = bh%8 (R6)
  const int yy  = blockIdx.y;
  const int p   = (yy < 8) ? yy : 23 - yy;         // CU pair (yy,yy+8): p+p'=15
  const int qlong = 31 - p, qshort = p;
  const int tid = threadIdx.x;
  const int wave = tid >> 6, lane = tid & 63;
  const int quad = lane >> 4, col = lane & 15;
  const int b = bh >> 4, h = bh & 15;
  const size_t base = (size_t)bh * 2048 * 64;
  const size_t vtb  = (size_t)bh * 64 * 2048;

  // staging map: 512 16B-chunks per tensor, 2 per thread
  int srow[2], sc8[2];
  #pragma unroll
  for (int i = 0; i < 2; ++i) {
    const int flat = tid + i * 256;
    srow[i] = flat >> 3;
    sc8[i]  = (flat & 7) * 8;
  }

  const int qa = qlong * 64 + wave * 16;    // long tile rows (always active)
  const int qb = qshort * 64 + wave * 16;   // short tile rows (active t<=qshort)
  const f16x8 bqa0 = *(const f16x8*)&Q[base + (size_t)(qa + col) * 64 + quad * 8];
  const f16x8 bqa1 = *(const f16x8*)&Q[base + (size_t)(qa + col) * 64 + 32 + quad * 8];
  const f16x8 bqb0 = *(const f16x8*)&Q[base + (size_t)(qb + col) * 64 + quad * 8];
  const f16x8 bqb1 = *(const f16x8*)&Q[base + (size_t)(qb + col) * 64 + 32 + quad * 8];

  f32x4 cta[4] = {}, ctb[4] = {};
  float la = 0.f, lb2 = 0.f;                // quad-partial row sums

  f16x8 kr[2], vr[2];
  auto gload = [&](int t) {
    #pragma unroll
    for (int i = 0; i < 2; ++i) {
      kr[i] = *(const f16x8*)&K[base + (size_t)(t * 64 + srow[i]) * 64 + sc8[i]];
      vr[i] = *(const f16x8*)&Vt[vtb + (size_t)srow[i] * 2048 + t * 64 + sc8[i]];
    }
  };
  auto swrite = [&](int buf) {
    #pragma unroll
    for (int i = 0; i < 2; ++i) {
      *(f16x8*)&Ks[buf][srow[i] * 72 + sc8[i]]  = kr[i];
      *(f16x8*)&Vts[buf][srow[i] * 72 + sc8[i]] = vr[i];
    }
  };

  const int nIter = qlong + 1;               // 17..32

  // prologue: stage tile 0 into buf0, prefetch tile 1 into regs
  gload(0);
  __syncthreads();
  swrite(0);
  gload(1);                                  // nIter >= 17 always

  for (int t = 0; t < nIter; ++t) {
    const int cur = t & 1;
    __syncthreads();                         // buf[cur] staged; own vmcnt drained
    if (t + 1 < nIter) {
      swrite(cur ^ 1);                       // stage next tile
      if (t + 2 < nIter) gload(t + 2);       // refill regs
    }
    const bool doB = (t <= qshort);

    // S^T = K Q^T for both tiles; ak frags shared from registers
    f32x4 sa[4], sb[4];
    __builtin_amdgcn_s_setprio(1);
    #pragma unroll
    for (int jt = 0; jt < 4; ++jt) {
      const int kro = (jt * 16 + col) * 72;
      const f16x8 ak0 = *(const f16x8*)&Ks[cur][kro + quad * 8];
      const f16x8 ak1 = *(const f16x8*)&Ks[cur][kro + 32 + quad * 8];
      f32x4 za = {};
      za = mfma16(ak0, bqa0, za);
      sa[jt] = mfma16(ak1, bqa1, za);
      if (doB) {
        f32x4 zb = {};
        zb = mfma16(ak0, bqb0, zb);
        sb[jt] = mfma16(ak1, bqb1, zb);
      }
    }
    __builtin_amdgcn_s_setprio(0);

    if (t == qlong) {   // long tile diagonal (last iteration)
      #pragma unroll
      for (int jt = 0; jt < 4; ++jt) {
        const int kg = t * 64 + jt * 16 + quad * 4;
        #pragma unroll
        for (int r = 0; r < 4; ++r)
          if (kg + r > qa + col) sa[jt][r] = -1e30f;
      }
    }
    if (t == qshort) {  // short tile diagonal
      #pragma unroll
      for (int jt = 0; jt < 4; ++jt) {
        const int kg = t * 64 + jt * 16 + quad * 4;
        #pragma unroll
        for (int r = 0; r < 4; ++r)
          if (kg + r > qb + col) sb[jt][r] = -1e30f;
      }
    }

    const f16x2 one2 = {(_Float16)1.f, (_Float16)1.f};

    // ---- P = exp2(s) (static-max), long tile -> Ps slot 0 ----
    {
      float rs = 0.f;
      #pragma unroll
      for (int jt = 0; jt < 4; ++jt) {
        const f16x2 a01 = pkrtz(fexp2(sa[jt][0]), fexp2(sa[jt][1]));
        const f16x2 a23 = pkrtz(fexp2(sa[jt][2]), fexp2(sa[jt][3]));
        rs = dot2acc(a01, one2, rs);
        rs = dot2acc(a23, one2, rs);
        f16x4 pw; pw[0] = a01[0]; pw[1] = a01[1]; pw[2] = a23[0]; pw[3] = a23[1];
        *(f16x4*)&Ps[wave][0][col * 72 + jt * 16 + quad * 4] = pw;
      }
      la += rs;
    }

    // ---- P = exp2(s), short tile -> Ps slot 1 ----
    if (doB) {
      float rs = 0.f;
      #pragma unroll
      for (int jt = 0; jt < 4; ++jt) {
        const f16x2 a01 = pkrtz(fexp2(sb[jt][0]), fexp2(sb[jt][1]));
        const f16x2 a23 = pkrtz(fexp2(sb[jt][2]), fexp2(sb[jt][3]));
        rs = dot2acc(a01, one2, rs);
        rs = dot2acc(a23, one2, rs);
        f16x4 pw; pw[0] = a01[0]; pw[1] = a01[1]; pw[2] = a23[0]; pw[3] = a23[1];
        *(f16x4*)&Ps[wave][1][col * 72 + jt * 16 + quad * 4] = pw;
      }
      lb2 += rs;
    }

    __asm__ volatile("s_waitcnt lgkmcnt(0)" ::: "memory");  // in-wave P RAW drain

    // ---- ctx += P V (bv frags shared from registers) ----
    const f16x8 apa0 = *(const f16x8*)&Ps[wave][0][col * 72 + quad * 8];
    const f16x8 apa1 = *(const f16x8*)&Ps[wave][0][col * 72 + 32 + quad * 8];
    __builtin_amdgcn_s_setprio(1);
    if (doB) {
      const f16x8 apb0 = *(const f16x8*)&Ps[wave][1][col * 72 + quad * 8];
      const f16x8 apb1 = *(const f16x8*)&Ps[wave][1][col * 72 + 32 + quad * 8];
      #pragma unroll
      for (int jd = 0; jd < 4; ++jd) {
        const int vro = (jd * 16 + col) * 72;
        const f16x8 bv0 = *(const f16x8*)&Vts[cur][vro + quad * 8];
        const f16x8 bv1 = *(const f16x8*)&Vts[cur][vro + 32 + quad * 8];
        cta[jd] = mfma16(apa1, bv1, mfma16(apa0, bv0, cta[jd]));
        ctb[jd] = mfma16(apb1, bv1, mfma16(apb0, bv0, ctb[jd]));
      }
    } else {
      #pragma unroll
      for (int jd = 0; jd < 4; ++jd) {
        const int vro = (jd * 16 + col) * 72;
        const f16x8 bv0 = *(const f16x8*)&Vts[cur][vro + quad * 8];
        const f16x8 bv1 = *(const f16x8*)&Vts[cur][vro + 32 + quad * 8];
        cta[jd] = mfma16(apa1, bv1, mfma16(apa0, bv0, cta[jd]));
      }
    }
    __builtin_amdgcn_s_setprio(0);
  }

  // ---- epilogue, long tile ----
  {
    la += __shfl_xor(la, 16);
    la += __shfl_xor(la, 32);
    f32x4 lva;
    #pragma unroll
    for (int r = 0; r < 4; ++r) lva[r] = __shfl(la, quad * 4 + r);
    #pragma unroll
    for (int jd = 0; jd < 4; ++jd) {
      #pragma unroll
      for (int r = 0; r < 4; ++r) {
        const int qga = qa + quad * 4 + r;
        const int d = h * 64 + jd * 16 + col;
        ctx[((size_t)b * 2048 + qga) * 1024 + d] = (f16)(cta[jd][r] / lva[r]);
      }
    }
  }
  // ---- epilogue, short tile ----
  {
    lb2 += __shfl_xor(lb2, 16);
    lb2 += __shfl_xor(lb2, 32);
    f32x4 lvb;
    #pragma unroll
    for (int r = 0; r < 4; ++r) lvb[r] = __shfl(lb2, quad * 4 + r);
    #pragma unroll
    for (int jd = 0; jd < 4; ++jd) {
      #pragma unroll
      for (int r = 0; r < 4; ++r) {
        const int qgb = qb + quad * 4 + r;
        const int d = h * 64 + jd * 16 + col;
        ctx[((size_t)b * 2048 + qgb) * 1024 + d] = (f16)(ctb[jd][r] / lvb[r]);
      }
    }
  }
}

// ---------------- O projection: 128x64 tile, BK=64, dbuf 1-barrier --------
// REVERTED to R11 (known-good): __syncthreads dbuf, blocked-k [ks][row][32].
__global__ __launch_bounds__(256) void gemm_o(
    const f16* __restrict__ A, const f16* __restrict__ B, const float* __restrict__ bias,
    float* __restrict__ Out)
{
  constexpr int K = 1024;
  __shared__ __align__(16) f16 As[2][2][128 * 32];   // [buf][ks][row][32]
  __shared__ __align__(16) f16 Bs[2][2][64 * 32];    // [buf][ks][row][32]
  const int tid  = threadIdx.x;
  const int wave = tid >> 6, lane = tid & 63;
  const int quad = lane >> 4, col = lane & 15;
  const int tile_m = blockIdx.y * 128, tile_n = blockIdx.x * 64;
  const int mb = wave * 32;
  const int srow = lane >> 2, scol = (lane & 3) * 8;   // 16 rows x 32 cols per call
  const f16* gA = A + (size_t)(tile_m + srow) * K + scol;
  const f16* gB = B + (size_t)(tile_n + srow) * K + scol;

  auto stage = [&](int buf, int k0) {
    #pragma unroll
    for (int ks = 0; ks < 2; ++ks) {
      #pragma unroll
      for (int i = 0; i < 2; ++i)      // A: this wave's 32 rows, 16 per call
        gl2lds16(gA + (size_t)(wave * 32 + i * 16) * K + k0 + ks * 32,
                 &As[buf][ks][(wave * 32 + i * 16) * 32]);
      // B: this wave's 16 rows
      gl2lds16(gB + (size_t)(wave * 16) * K + k0 + ks * 32,
               &Bs[buf][ks][(wave * 16) * 32]);
    }
  };

  f32x4 acc[2][4] = {};
  stage(0, 0);
  for (int k0 = 0; k0 < K; k0 += 64) {
    const int cur = (k0 >> 6) & 1;
    __syncthreads();                     // buf[cur] landed (barrier drains vmcnt)
    if (k0 + 64 < K) stage(cur ^ 1, k0 + 64);
    #pragma unroll
    for (int ks = 0; ks < 2; ++ks) {
      f16x8 af[2], bf[4];
      #pragma unroll
      for (int i = 0; i < 2; ++i)
        af[i] = *(const f16x8*)&As[cur][ks][(mb + i * 16 + col) * 32 + quad * 8];
      #pragma unroll
      for (int j = 0; j < 4; ++j)
        bf[j] = *(const f16x8*)&Bs[cur][ks][(j * 16 + col) * 32 + quad * 8];
      #pragma unroll
      for (int i = 0; i < 2; ++i)
        #pragma unroll
        for (int j = 0; j < 4; ++j)
          acc[i][j] = mfma16(af[i], bf[j], acc[i][j]);
    }
  }

  #pragma unroll
  for (int j = 0; j < 4; ++j) {
    const int gn = tile_n + j * 16 + col;
    const float bvv = bias[gn];
    #pragma unroll
    for (int i = 0; i < 2; ++i) {
      #pragma unroll
      for (int r = 0; r < 4; ++r) {
        const int gm = tile_m + mb + i * 16 + quad * 4 + r;
        Out[(size_t)gm * 1024 + gn] = acc[i][j][r] + bvv;
      }
    }
  }
}

extern "C" void kernel_launch(void* const* d_in, const int* in_sizes, int n_in,
                              void* d_out, int out_size, void* d_ws, size_t ws_size,
                              hipStream_t stream)
{
  const float* x  = (const float*)d_in[0];
  const float* Wq = (const float*)d_in[1];
  const float* bq = (const float*)d_in[2];
  const float* Wk = (const float*)d_in[3];
  const float* bk = (const float*)d_in[4];
  const float* Wv = (const float*)d_in[5];
  const float* bv = (const float*)d_in[6];
  const float* Wo = (const float*)d_in[7];
  const float* bo = (const float*)d_in[8];
  float* out = (float*)d_out;

  f16* ws = (f16*)d_ws;
  const size_t M1 = 1048576;
  f16* xh    = ws;             // 4M halves
  f16* wqkvh = ws + 4  * M1;   // 3M
  f16* woh   = ws + 7  * M1;   // 1M
  f16* Qh    = ws + 8  * M1;   // 4M  [B,H,S,64] (pre-scaled)
  f16* Kh    = ws + 12 * M1;   // 4M  [B,H,S,64]
  f16* Vth   = ws + 20 * M1;   // 4M  [B,H,64,S] (written directly by gemm_qkv)
  f16* ctxh  = ws + 24 * M1;   // 4M  [B,S,D]

  cvt_kernel<<<4096, 256, 0, stream>>>(x, Wq, Wk, Wv, Wo, xh, wqkvh, woh);
  gemm_qkv<<<dim3(24, 32), 256, 0, stream>>>(xh, wqkvh, bq, bk, bv, Qh, Kh, Vth);
  attn_kernel<<<dim3(32, 16), 256, 0, stream>>>(Qh, Kh, Vth, ctxh);
  gemm_o<<<dim3(16, 32), 256, 0, stream>>>(ctxh, woh, bo, out);
}